// Round 2
// baseline (142.926 us; speedup 1.0000x reference)
//
#include <hip/hip_runtime.h>
#include <hip/hip_bf16.h>

#define NUM_CLASSES 64
#define BATCH 16
#define CHAN 3
#define HW (512 * 512)
#define BPB 64          // blocks per batch image
#define THREADS 256
#define NREP 4          // histogram replicas to cut LDS-atomic contention

// ---------------------------------------------------------------------------
// Kernel 1: per-(batch,class) sum of per-pixel channel-summed |in - tgt|,
// plus pixel counts.  Block handles a contiguous slab of one batch image, so
// LDS histogram only needs 64 bins (replicated NREP x).
// ---------------------------------------------------------------------------
__global__ __launch_bounds__(THREADS) void frl_accum(
    const float4* __restrict__ inp,   // [B,C,H,W] as float4
    const float4* __restrict__ tgt,
    const int4* __restrict__ mask,    // [B,H,W] as int4
    float* __restrict__ g_sum,        // [B*64]
    unsigned int* __restrict__ g_cnt) // [B*64]
{
    __shared__ float s_sum[NREP][NUM_CLASSES];
    __shared__ unsigned int s_cnt[NREP][NUM_CLASSES];
    const int t = threadIdx.x;
    for (int i = t; i < NREP * NUM_CLASSES; i += THREADS) {
        ((float*)s_sum)[i] = 0.0f;
        ((unsigned int*)s_cnt)[i] = 0u;
    }
    __syncthreads();

    const int b   = blockIdx.x / BPB;
    const int blk = blockIdx.x % BPB;
    const int PPB = HW / BPB;                 // 4096 pixels per block
    const int GPB = PPB / 4;                  // 1024 float4-groups per block
    const int rep = t & (NREP - 1);

    const int g0    = blk * GPB;              // first group of this block
    const int cbase = b * (CHAN * HW / 4);    // float4 units
    const int mbase = b * (HW / 4);           // int4 units

    for (int g = t; g < GPB; g += THREADS) {
        const int4 m4 = mask[mbase + g0 + g];
        float l[4] = {0.f, 0.f, 0.f, 0.f};
        #pragma unroll
        for (int c = 0; c < CHAN; ++c) {
            const int idx = cbase + c * (HW / 4) + g0 + g;
            const float4 a = inp[idx];
            const float4 v = tgt[idx];
            l[0] += fabsf(a.x - v.x);
            l[1] += fabsf(a.y - v.y);
            l[2] += fabsf(a.z - v.z);
            l[3] += fabsf(a.w - v.w);
        }
        atomicAdd(&s_sum[rep][m4.x], l[0]);
        atomicAdd(&s_sum[rep][m4.y], l[1]);
        atomicAdd(&s_sum[rep][m4.z], l[2]);
        atomicAdd(&s_sum[rep][m4.w], l[3]);
        atomicAdd(&s_cnt[rep][m4.x], 1u);
        atomicAdd(&s_cnt[rep][m4.y], 1u);
        atomicAdd(&s_cnt[rep][m4.z], 1u);
        atomicAdd(&s_cnt[rep][m4.w], 1u);
    }
    __syncthreads();
    if (t < NUM_CLASSES) {
        float fs = 0.0f;
        unsigned int cs = 0u;
        #pragma unroll
        for (int r = 0; r < NREP; ++r) { fs += s_sum[r][t]; cs += s_cnt[r][t]; }
        atomicAdd(&g_sum[b * NUM_CLASSES + t], fs);
        atomicAdd(&g_cnt[b * NUM_CLASSES + t], cs);
    }
}

// ---------------------------------------------------------------------------
// Kernel 2: avg = sum / max(3*cnt,1); max over avg; result =
//   ( Σ sums + Σ sums * clip(avg/max,0,1) ) / (B*C*H*W)     (BETA = 1)
// ---------------------------------------------------------------------------
__global__ __launch_bounds__(256) void frl_finalize(
    const float* __restrict__ g_sum,
    const unsigned int* __restrict__ g_cnt,
    float* __restrict__ out)
{
    const int NSEG = BATCH * NUM_CLASSES;     // 1024
    __shared__ float s_avg[BATCH * NUM_CLASSES];
    __shared__ float red[256];
    const int t = threadIdx.x;

    float lmax = 0.0f;
    for (int s = t; s < NSEG; s += 256) {
        const float sum = g_sum[s];
        const float cnt = (float)g_cnt[s];
        const float avg = sum / fmaxf(cnt * (float)CHAN, 1.0f);
        s_avg[s] = avg;
        lmax = fmaxf(lmax, avg);
    }
    red[t] = lmax;
    __syncthreads();
    for (int off = 128; off > 0; off >>= 1) {
        if (t < off) red[t] = fmaxf(red[t], red[t + off]);
        __syncthreads();
    }
    const float maxavg = fmaxf(red[0], 1e-30f);
    __syncthreads();

    float part = 0.0f;
    for (int s = t; s < NSEG; s += 256) {
        const float w = fminf(fmaxf(s_avg[s] / maxavg, 0.0f), 1.0f);
        part += g_sum[s] * (1.0f + w);
    }
    red[t] = part;
    __syncthreads();
    for (int off = 128; off > 0; off >>= 1) {
        if (t < off) red[t] += red[t + off];
        __syncthreads();
    }
    if (t == 0) {
        out[0] = red[0] / (float)((size_t)BATCH * CHAN * HW);
    }
}

extern "C" void kernel_launch(void* const* d_in, const int* in_sizes, int n_in,
                              void* d_out, int out_size, void* d_ws, size_t ws_size,
                              hipStream_t stream) {
    const float4* inp = (const float4*)d_in[0];
    const float4* tgt = (const float4*)d_in[1];
    const int4* mask  = (const int4*)d_in[2];

    float* g_sum        = (float*)d_ws;
    unsigned int* g_cnt = (unsigned int*)((char*)d_ws + BATCH * NUM_CLASSES * sizeof(float));

    hipMemsetAsync(d_ws, 0, 2 * BATCH * NUM_CLASSES * sizeof(float), stream);
    frl_accum<<<BATCH * BPB, THREADS, 0, stream>>>(inp, tgt, mask, g_sum, g_cnt);
    frl_finalize<<<1, 256, 0, stream>>>(g_sum, g_cnt, (float*)d_out);
}

// Round 3
// 142.349 us; speedup vs baseline: 1.0041x; 1.0041x over previous
//
#include <hip/hip_runtime.h>
#include <hip/hip_bf16.h>

#define NUM_CLASSES 64
#define BATCH 16
#define CHAN 3
#define HW (512 * 512)
#define BPB 128         // blocks per batch image -> 2048 blocks total
#define THREADS 256
#define NREP 4          // histogram replicas to cut LDS-atomic contention
#define CPAD 8          // pad per replica row: stagger replica banks by 8

// ---------------------------------------------------------------------------
// Kernel 1: per-(batch,class) sum of per-pixel channel-summed |in - tgt|,
// plus pixel counts.  Block handles a contiguous slab of one batch image.
// Two group-iterations fully unrolled with ALL loads hoisted -> 13 loads in
// flight before first use (ILP), 8 blocks/CU (TLP).
// ---------------------------------------------------------------------------
__global__ __launch_bounds__(THREADS) void frl_accum(
    const float4* __restrict__ inp,   // [B,C,H,W] as float4
    const float4* __restrict__ tgt,
    const int4* __restrict__ mask,    // [B,H,W] as int4
    float* __restrict__ g_sum,        // [B*64]
    unsigned int* __restrict__ g_cnt) // [B*64]
{
    __shared__ float s_sum[NREP][NUM_CLASSES + CPAD];
    __shared__ unsigned int s_cnt[NREP][NUM_CLASSES + CPAD];
    const int t = threadIdx.x;
    for (int i = t; i < NREP * (NUM_CLASSES + CPAD); i += THREADS) {
        ((float*)s_sum)[i] = 0.0f;
        ((unsigned int*)s_cnt)[i] = 0u;
    }
    __syncthreads();

    const int b   = blockIdx.x / BPB;
    const int blk = blockIdx.x % BPB;
    const int GPB = HW / 4 / BPB;             // 512 float4-groups per block
    const int rep = t & (NREP - 1);

    const int g0    = blk * GPB;
    const int cbase = b * (CHAN * HW / 4);    // float4 units
    const int mbase = b * (HW / 4);           // int4 units
    const int CS    = HW / 4;                 // channel stride in float4

    const int ga = g0 + t;                    // iter A group
    const int gb = g0 + t + THREADS;          // iter B group

    // ---- hoisted loads: 2 mask + 12 data, all independent ----
    const int4 ma = mask[mbase + ga];
    const int4 mb = mask[mbase + gb];
    const float4 ia0 = inp[cbase + 0 * CS + ga];
    const float4 ta0 = tgt[cbase + 0 * CS + ga];
    const float4 ia1 = inp[cbase + 1 * CS + ga];
    const float4 ta1 = tgt[cbase + 1 * CS + ga];
    const float4 ia2 = inp[cbase + 2 * CS + ga];
    const float4 ta2 = tgt[cbase + 2 * CS + ga];
    const float4 ib0 = inp[cbase + 0 * CS + gb];
    const float4 tb0 = tgt[cbase + 0 * CS + gb];
    const float4 ib1 = inp[cbase + 1 * CS + gb];
    const float4 tb1 = tgt[cbase + 1 * CS + gb];
    const float4 ib2 = inp[cbase + 2 * CS + gb];
    const float4 tb2 = tgt[cbase + 2 * CS + gb];

    // ---- per-pixel channel-summed L1 ----
    const float la0 = fabsf(ia0.x - ta0.x) + fabsf(ia1.x - ta1.x) + fabsf(ia2.x - ta2.x);
    const float la1 = fabsf(ia0.y - ta0.y) + fabsf(ia1.y - ta1.y) + fabsf(ia2.y - ta2.y);
    const float la2 = fabsf(ia0.z - ta0.z) + fabsf(ia1.z - ta1.z) + fabsf(ia2.z - ta2.z);
    const float la3 = fabsf(ia0.w - ta0.w) + fabsf(ia1.w - ta1.w) + fabsf(ia2.w - ta2.w);
    const float lb0 = fabsf(ib0.x - tb0.x) + fabsf(ib1.x - tb1.x) + fabsf(ib2.x - tb2.x);
    const float lb1 = fabsf(ib0.y - tb0.y) + fabsf(ib1.y - tb1.y) + fabsf(ib2.y - tb2.y);
    const float lb2 = fabsf(ib0.z - tb0.z) + fabsf(ib1.z - tb1.z) + fabsf(ib2.z - tb2.z);
    const float lb3 = fabsf(ib0.w - tb0.w) + fabsf(ib1.w - tb1.w) + fabsf(ib2.w - tb2.w);

    // ---- LDS histogram ----
    atomicAdd(&s_sum[rep][ma.x], la0);
    atomicAdd(&s_sum[rep][ma.y], la1);
    atomicAdd(&s_sum[rep][ma.z], la2);
    atomicAdd(&s_sum[rep][ma.w], la3);
    atomicAdd(&s_sum[rep][mb.x], lb0);
    atomicAdd(&s_sum[rep][mb.y], lb1);
    atomicAdd(&s_sum[rep][mb.z], lb2);
    atomicAdd(&s_sum[rep][mb.w], lb3);
    atomicAdd(&s_cnt[rep][ma.x], 1u);
    atomicAdd(&s_cnt[rep][ma.y], 1u);
    atomicAdd(&s_cnt[rep][ma.z], 1u);
    atomicAdd(&s_cnt[rep][ma.w], 1u);
    atomicAdd(&s_cnt[rep][mb.x], 1u);
    atomicAdd(&s_cnt[rep][mb.y], 1u);
    atomicAdd(&s_cnt[rep][mb.z], 1u);
    atomicAdd(&s_cnt[rep][mb.w], 1u);

    __syncthreads();
    if (t < NUM_CLASSES) {
        float fs = 0.0f;
        unsigned int cs = 0u;
        #pragma unroll
        for (int r = 0; r < NREP; ++r) { fs += s_sum[r][t]; cs += s_cnt[r][t]; }
        atomicAdd(&g_sum[b * NUM_CLASSES + t], fs);
        atomicAdd(&g_cnt[b * NUM_CLASSES + t], cs);
    }
}

// ---------------------------------------------------------------------------
// Kernel 2: avg = sum / max(3*cnt,1); max over avg; result =
//   ( Σ sums + Σ sums * clip(avg/max,0,1) ) / (B*C*H*W)     (BETA = 1)
// ---------------------------------------------------------------------------
__global__ __launch_bounds__(256) void frl_finalize(
    const float* __restrict__ g_sum,
    const unsigned int* __restrict__ g_cnt,
    float* __restrict__ out)
{
    const int NSEG = BATCH * NUM_CLASSES;     // 1024
    __shared__ float s_avg[BATCH * NUM_CLASSES];
    __shared__ float red[256];
    const int t = threadIdx.x;

    float lmax = 0.0f;
    for (int s = t; s < NSEG; s += 256) {
        const float sum = g_sum[s];
        const float cnt = (float)g_cnt[s];
        const float avg = sum / fmaxf(cnt * (float)CHAN, 1.0f);
        s_avg[s] = avg;
        lmax = fmaxf(lmax, avg);
    }
    red[t] = lmax;
    __syncthreads();
    for (int off = 128; off > 0; off >>= 1) {
        if (t < off) red[t] = fmaxf(red[t], red[t + off]);
        __syncthreads();
    }
    const float maxavg = fmaxf(red[0], 1e-30f);
    __syncthreads();

    float part = 0.0f;
    for (int s = t; s < NSEG; s += 256) {
        const float w = fminf(fmaxf(s_avg[s] / maxavg, 0.0f), 1.0f);
        part += g_sum[s] * (1.0f + w);
    }
    red[t] = part;
    __syncthreads();
    for (int off = 128; off > 0; off >>= 1) {
        if (t < off) red[t] += red[t + off];
        __syncthreads();
    }
    if (t == 0) {
        out[0] = red[0] / (float)((size_t)BATCH * CHAN * HW);
    }
}

extern "C" void kernel_launch(void* const* d_in, const int* in_sizes, int n_in,
                              void* d_out, int out_size, void* d_ws, size_t ws_size,
                              hipStream_t stream) {
    const float4* inp = (const float4*)d_in[0];
    const float4* tgt = (const float4*)d_in[1];
    const int4* mask  = (const int4*)d_in[2];

    float* g_sum        = (float*)d_ws;
    unsigned int* g_cnt = (unsigned int*)((char*)d_ws + BATCH * NUM_CLASSES * sizeof(float));

    hipMemsetAsync(d_ws, 0, 2 * BATCH * NUM_CLASSES * sizeof(float), stream);
    frl_accum<<<BATCH * BPB, THREADS, 0, stream>>>(inp, tgt, mask, g_sum, g_cnt);
    frl_finalize<<<1, 256, 0, stream>>>(g_sum, g_cnt, (float*)d_out);
}